// Round 10
// baseline (453.309 us; speedup 1.0000x reference)
//
#include <hip/hip_runtime.h>

// ============================================================================
// GQA prefill: B=4, S=2048, DIM=1152, NH=8, KVH=2, HD=144, causal, start_pos=0
//
// R17 = R10 inner loop (PASSING) restructured as SPLIT-K (flash-decoding).
// Why: R10/R14/R16 proved schedule micro-changes don't move attn (176-185us).
// OccupancyPercent ~28% (= ~9/32 waves) exposed the real issue: co-resident
// block pairs (qi, 31-qi) have equal TOTAL work but unequal DURATION -- the
// long (64-tile) block runs nearly the whole kernel with only 8 waves
// (2/SIMD), too few to hide per-tile serial chains.
// Fix: each block = ONE CHUNK of <=16 k-tiles of one (q-tile, head-pair).
//  - grid (80,4,4) = 1280 blocks; slot x enumerates (qi, c): nc=ceil(nkt/16).
//  - inner loop R10-VERBATIM (DMA stage->sync->compute->sync, unconditional
//    rescale, band = kt >= nkt-2 which provably fires only in the last chunk)
//    over kt in [16c, min(16c+16, nkt)).
//  - epilogue writes PARTIALS: O (f16, pre-normalized) + m,l (f32) into the
//    dead qkv ws region (qkv is consumed by rope/v_transpose before attn;
//    partials = 48.5 MB < region's 56.6 MB).
//  - merge kernel: per row, M=max m_i; out = (sum e^{m_i-M} O_i) /
//    (sum e^{m_i-M} l_i)  == exact softmax algebraically. Writes swizzled
//    attn_sw granules (f16x8, fully coalesced).
//  - LDS 28672 B + launch_bounds(512,4) -> up to 4 chunk-blocks (32 waves)
//    resident per CU for the entire kernel.
//
// R10 (unchanged): head-pair sharing: waves 0-3 -> head hp*2, waves 4-7 ->
// head hp*2+1 (kvh = hp>>1 block-uniform) share one staged K/V tile; per-wave
// R7-exact TQ=64 strip (w4 = w&3), TK=32.
//
// R7 (unchanged): K and Vt pre-swizzled into MFMA-granule order:
//      Ksw granule = (tile*576 + (d>>3)*32 + (s&31)), elem d&7
//      Vsw granule = (tile*576 + ((s&31)>>3)*144 + d), elem s&7
//
// ws layout (bytes):
//   x_sw     :         0 ..  18874368   (8192x1152 f16 swizzled, KC=144)
//   wqkv_sw  :  18874368 ..  23003136   (1792x1152 sw; rows>=1728 pad)
//   wo_sw    :  23003136 ..  25657344
//   bias_qkv :  25657344 ..  25664256
//   qkv f32  :  25664256 ..  82287360   (8192x1728 plain)
//     during attention this region is reused:
//     part_O  :  25664256 ..  72850176   [1280][2][64][144] f16
//     part_ml :  72850176 ..  74160896   [1280][2][64][2]  f32
//   Qh       :  82287360 .. 101161728   (4,8,2048,144) f16 plain
//   Ksw      : 101161728 .. 105880320   (4,2) x 64 tiles x 576 granules
//   Vsw      : 105880320 .. 110598912   (4,2) x 64 tiles x 576 granules
//   attn_sw  : 110598912 .. 129473280   (8192x1152 f16 swizzled)
// ============================================================================

#define THREADS 256

typedef _Float16 f16x8 __attribute__((ext_vector_type(8)));
typedef _Float16 f16x4 __attribute__((ext_vector_type(4)));
typedef _Float16 f16x2 __attribute__((ext_vector_type(2)));
typedef float f32x4 __attribute__((ext_vector_type(4)));

// 16B global->LDS DMA: LDS dst = wave-uniform base + lane*16
#define GLDS16(gp, lp)                                                  \
  __builtin_amdgcn_global_load_lds(                                     \
      (const __attribute__((address_space(1))) unsigned int*)(gp),      \
      (__attribute__((address_space(3))) unsigned int*)(lp), 16, 0, 0)

// ---------------------------------------------------------------- cvt -> swizzled
__global__ __launch_bounds__(THREADS) void cvt_sw(const float* __restrict__ in,
                                                  _Float16* __restrict__ out,
                                                  int nG, int KC, int nrows) {
  int i = blockIdx.x * THREADS + threadIdx.x;
  if (i >= nG) return;
  int rr = i & 127;
  int j = i >> 7;
  int kc = j % KC;
  int rb = j / KC;
  int R = rb * 128 + rr;
  if (R >= nrows) R = nrows - 1;
  const float* src = in + (size_t)R * (KC * 8) + kc * 8;
  float4 a = *(const float4*)src;
  float4 c = *(const float4*)(src + 4);
  f16x8 o;
  o[0] = (_Float16)a.x; o[1] = (_Float16)a.y;
  o[2] = (_Float16)a.z; o[3] = (_Float16)a.w;
  o[4] = (_Float16)c.x; o[5] = (_Float16)c.y;
  o[6] = (_Float16)c.z; o[7] = (_Float16)c.w;
  *(f16x8*)(out + (size_t)i * 8) = o;
}

// ---------------------------------------------------------------- bias concat
__global__ __launch_bounds__(THREADS) void prep_bias(const float* __restrict__ bq,
                                                     const float* __restrict__ bkv,
                                                     float* __restrict__ bias) {
  int i = blockIdx.x * THREADS + threadIdx.x;
  if (i < 1152) bias[i] = bq[i];
  else if (i < 1728) bias[i] = bkv[i - 1152];
}

// ---------------------------------------------------------------- GEMM (swizzled)
__global__ __launch_bounds__(THREADS) void gemm_sw(
    const _Float16* __restrict__ A, const _Float16* __restrict__ B,
    const float* __restrict__ bias, float* __restrict__ C, int M, int N, int K) {
  __shared__ __align__(16) _Float16 As[1024 * 8];
  __shared__ __align__(16) _Float16 Bs[1024 * 8];
  const int t = threadIdx.x;
  const int w = t >> 6, lane = t & 63;
  const int quad = lane >> 4, l16 = lane & 15;
  const int wm = (w & 1) << 6, wn = (w >> 1) << 6;
  const int KC = K >> 3;
  const int mb = blockIdx.y, nb = blockIdx.x;
  const int m0 = mb << 7, n0 = nb << 7;

  f32x4 acc[4][4] = {};

  for (int kcb = 0; kcb < KC; kcb += 8) {
    const size_t Ab = ((size_t)mb * KC + kcb) << 7;
    const size_t Bb = ((size_t)nb * KC + kcb) << 7;
#pragma unroll
    for (int j = 0; j < 4; ++j) {
      const int ii = (w << 2) + j;
      GLDS16(A + ((Ab + (ii << 6) + lane) << 3), &As[(ii << 6) * 8]);
      GLDS16(B + ((Bb + (ii << 6) + lane) << 3), &Bs[(ii << 6) * 8]);
    }
    __syncthreads();
#pragma unroll
    for (int ks = 0; ks < 2; ++ks) {
      f16x8 af[4], bf[4];
#pragma unroll
      for (int mi = 0; mi < 4; ++mi)
        af[mi] = *(const f16x8*)&As[((((ks << 2) + quad) << 7) + wm + (mi << 4) + l16) * 8];
#pragma unroll
      for (int ni = 0; ni < 4; ++ni)
        bf[ni] = *(const f16x8*)&Bs[((((ks << 2) + quad) << 7) + wn + (ni << 4) + l16) * 8];
#pragma unroll
      for (int mi = 0; mi < 4; ++mi)
#pragma unroll
        for (int ni = 0; ni < 4; ++ni)
          acc[mi][ni] =
              __builtin_amdgcn_mfma_f32_16x16x32_f16(af[mi], bf[ni], acc[mi][ni], 0, 0, 0);
    }
    __syncthreads();
  }

#pragma unroll
  for (int mi = 0; mi < 4; ++mi) {
    const int row = m0 + wm + (mi << 4) + (quad << 2);
#pragma unroll
    for (int ni = 0; ni < 4; ++ni) {
      const int col = n0 + wn + (ni << 4) + l16;
      if (col < N) {
        const float bv = bias[col];
#pragma unroll
        for (int r = 0; r < 4; ++r)
          C[(size_t)(row + r) * N + col] = acc[mi][ni][r] + bv;
      }
    }
  }
}

// ---------------------------------------------------------------- RoPE
__global__ __launch_bounds__(THREADS) void rope_scatter_f16(
    const float* __restrict__ qkv, const float* __restrict__ fc,
    const float* __restrict__ fs, _Float16* __restrict__ Qh,
    _Float16* __restrict__ Ksw) {
  int idx = blockIdx.x * THREADS + threadIdx.x;
  int m = idx / 720;
  int c = idx - m * 720;
  int s = m & 2047, b = m >> 11;
  const float* row = qkv + (size_t)m * 1728;
  int h, d2;
  const float* src;
  _Float16* dst;
  if (c < 576) {
    h = c / 72;
    d2 = c - h * 72;
    src = row + h * 144 + 2 * d2;
    dst = Qh + ((size_t)(b * 8 + h) * 2048 + s) * 144 + 2 * d2;
  } else {
    int cc = c - 576;
    h = cc / 72;  // kvh
    d2 = cc - h * 72;
    src = row + 1152 + h * 144 + 2 * d2;
    size_t g = ((size_t)(b * 2 + h) * 64 + (s >> 5)) * 576 + (d2 >> 2) * 32 + (s & 31);
    dst = Ksw + g * 8 + (d2 & 3) * 2;
  }
  float2 v = *(const float2*)src;
  float cth = fc[s * 72 + d2], sth = fs[s * 72 + d2];
  f16x2 o;
  o.x = (_Float16)(v.x * cth - v.y * sth);
  o.y = (_Float16)(v.x * sth + v.y * cth);
  *(f16x2*)dst = o;
}

// ---------------------------------------------------------------- V -> swizzled
__global__ __launch_bounds__(THREADS) void v_transpose(const float* __restrict__ qkv,
                                                       _Float16* __restrict__ Vsw) {
  __shared__ _Float16 tile[128 * 145];
  const int t = threadIdx.x;
  const int s0 = blockIdx.x * 128;
  const int kvh = blockIdx.y, b = blockIdx.z;
  const float* src = qkv + ((size_t)(b * 2048 + s0)) * 1728 + 1440 + kvh * 144;
#pragma unroll
  for (int i = 0; i < 18; ++i) {
    int c = t + i * 256;
    int r = c / 36, cc = c - r * 36;
    float4 v = *(const float4*)(src + (size_t)r * 1728 + cc * 4);
    int base = r * 145 + cc * 4;
    tile[base + 0] = (_Float16)v.x;
    tile[base + 1] = (_Float16)v.y;
    tile[base + 2] = (_Float16)v.z;
    tile[base + 3] = (_Float16)v.w;
  }
  __syncthreads();
  const size_t tb = ((size_t)(b * 2 + kvh) * 64 + (s0 >> 5)) * 576;
#pragma unroll
  for (int i = 0; i < 9; ++i) {
    int c = t + i * 256;
    int sc = c / 144, d = c - sc * 144;
    f16x8 o;
#pragma unroll
    for (int j = 0; j < 8; ++j) o[j] = tile[(sc * 8 + j) * 145 + d];
    size_t g = tb + (size_t)(sc >> 2) * 576 + (sc & 3) * 144 + d;
    *(f16x8*)(Vsw + g * 8) = o;
  }
}

// ---------------------------------------------------------------- MFMA flash attention (split-K chunk)
// Block (x, hp, b): slot x in [0,80) enumerates (qi, c): qi<8 1 chunk;
// 8-15 2 chunks; 16-23 3; 24-31 4 (chunk = 16 k-tiles). Waves 0-3 head hp*2,
// waves 4-7 head hp*2+1 share staged K/V. Inner loop = R10 verbatim over
// kt in [16c, min(16c+16,nkt)). Writes partial O (f16) + m,l (f32).
// LDS 28672 B; launch_bounds(512,4) -> 4 blocks (32 waves)/CU.
#define STAGE_TILE(kt)                                                     \
  do {                                                                     \
    const _Float16* Kt_ = Ksw + (tbase + (size_t)(kt)) * 4608;             \
    const _Float16* Vt_ = Vsw + (tbase + (size_t)(kt)) * 4608;             \
    for (int cc_ = w; cc_ < 18; cc_ += 8) {                                \
      if (cc_ < 9)                                                         \
        GLDS16(Kt_ + ((cc_ << 6) + lane) * 8, &Ks[(cc_ << 6) * 8]);        \
      else                                                                 \
        GLDS16(Vt_ + (((cc_ - 9) << 6) + lane) * 8,                        \
               &Vs[((cc_ - 9) << 6) * 8]);                                 \
    }                                                                      \
  } while (0)

__global__ __launch_bounds__(512, 4) void attn_mfma(
    const _Float16* __restrict__ Qh, const _Float16* __restrict__ Ksw,
    const _Float16* __restrict__ Vsw, _Float16* __restrict__ pO,
    float* __restrict__ pml) {
  __shared__ __align__(16) _Float16 Ks[576 * 8];
  __shared__ __align__(16) _Float16 Vs[576 * 8];
  __shared__ __align__(16) _Float16 Ps[128 * 40];
  const int t = threadIdx.x;
  const int w = t >> 6, lane = t & 63;
  const int w4 = w & 3;
  const int quad = lane >> 4, l16 = lane & 15;
  const int x = blockIdx.x, hp = blockIdx.y, b = blockIdx.z;
  const int h = hp * 2 + (w >> 2);
  const int kvh = hp >> 1;

  // slot x -> (qi, c)
  int qi, c;
  if (x < 8)       { qi = x;                 c = 0; }
  else if (x < 24) { qi = 8 + ((x - 8) >> 1);  c = (x - 8) & 1; }
  else if (x < 48) { qi = 16 + (x - 24) / 3;   c = (x - 24) % 3; }
  else             { qi = 24 + ((x - 48) >> 2); c = (x - 48) & 3; }

  const int q0 = qi * 64;
  const int nkt = 2 * qi + 2;                  // full k-tile count for this q-tile
  const int k0 = c * 16;
  const int kend = (k0 + 16 < nkt) ? k0 + 16 : nkt;
  const _Float16* Qg = Qh + ((size_t)(b * 8 + h) * 2048 + q0) * 144;
  const size_t tbase = (size_t)(b * 2 + kvh) * 64;

  // Q fragments: rows w4*16 + l16
  f16x8 qf[4];
  f16x4 qt4;
  {
    const _Float16* qp = Qg + (size_t)(w4 * 16 + l16) * 144;
#pragma unroll
    for (int ks = 0; ks < 4; ++ks) qf[ks] = *(const f16x8*)(qp + ks * 32 + quad * 8);
    qt4 = *(const f16x4*)(qp + 128 + quad * 4);
  }

  f32x4 Oacc[9] = {};
  float mrow[4] = {-3e38f, -3e38f, -3e38f, -3e38f};
  float lrow[4] = {0.f, 0.f, 0.f, 0.f};
  const float scale = 0.08333333333333333f;  // 1/sqrt(144)
  const int colb = (l16 & ~1);
  const int rsel = (lane & 1) << 1;

  for (int kt = k0; kt < kend; ++kt) {
    STAGE_TILE(kt);
    __syncthreads();

    // ---- QK^T: 16 rows x 32 keys
    f32x4 sc[2] = {};
#pragma unroll
    for (int ks = 0; ks < 4; ++ks) {
#pragma unroll
      for (int ct = 0; ct < 2; ++ct) {
        f16x8 bfr = *(const f16x8*)&Ks[(((ks * 4 + quad) << 5) + ct * 16 + l16) * 8];
        sc[ct] = __builtin_amdgcn_mfma_f32_16x16x32_f16(qf[ks], bfr, sc[ct], 0, 0, 0);
      }
    }
#pragma unroll
    for (int ct = 0; ct < 2; ++ct) {  // k=128..143 tail (legacy 16x16x16)
      f16x4 bt = *(const f16x4*)&Ks[(((16 + (quad >> 1)) << 5) + ct * 16 + l16) * 8 +
                                    (quad & 1) * 4];
      sc[ct] = __builtin_amdgcn_mfma_f32_16x16x16f16(qt4, bt, sc[ct], 0, 0, 0);
    }

    // ---- online softmax (rows q0+w4*16+quad*4+r, cols kt*32+ct*16+l16)
    const bool band = (kt >= nkt - 2);   // fires only in the last chunk
    const int rowb = q0 + w4 * 16 + quad * 4;
    float vv[2][4];
    float mx[4] = {-3e38f, -3e38f, -3e38f, -3e38f};
#pragma unroll
    for (int ct = 0; ct < 2; ++ct) {
      const int cb = kt * 32 + ct * 16 + l16;
#pragma unroll
      for (int r = 0; r < 4; ++r) {
        float v = sc[ct][r] * scale;
        if (band && cb > rowb + r) v -= 1e9f;
        vv[ct][r] = v;
        mx[r] = fmaxf(mx[r], v);
      }
    }
    float alv[4];
#pragma unroll
    for (int r = 0; r < 4; ++r) {
      float m = mx[r];
      m = fmaxf(m, __shfl_xor(m, 1));
      m = fmaxf(m, __shfl_xor(m, 2));
      m = fmaxf(m, __shfl_xor(m, 4));
      m = fmaxf(m, __shfl_xor(m, 8));
      float mn = fmaxf(mrow[r], m);
      alv[r] = __expf(mrow[r] - mn);
      mrow[r] = mn;
    }
    float rs[4] = {0.f, 0.f, 0.f, 0.f};
#pragma unroll
    for (int ct = 0; ct < 2; ++ct) {
      float p[4], q[4];
#pragma unroll
      for (int r = 0; r < 4; ++r) {
        p[r] = __expf(vv[ct][r] - mrow[r]);
        rs[r] += p[r];
      }
#pragma unroll
      for (int r = 0; r < 4; ++r) q[r] = __shfl_xor(p[r], 1);
#pragma unroll
      for (int k = 0; k < 2; ++k) {
        const int r = rsel + k;
        f16x2 pv;
        if (lane & 1) {
          pv.x = (_Float16)q[r];
          pv.y = (_Float16)p[r];
        } else {
          pv.x = (_Float16)p[r];
          pv.y = (_Float16)q[r];
        }
        *(f16x2*)&Ps[(w * 16 + quad * 4 + r) * 40 + ct * 16 + colb] = pv;
      }
    }
#pragma unroll
    for (int r = 0; r < 4; ++r) {
      float v = rs[r];
      v += __shfl_xor(v, 1);
      v += __shfl_xor(v, 2);
      v += __shfl_xor(v, 4);
      v += __shfl_xor(v, 8);
      lrow[r] = lrow[r] * alv[r] + v;
    }
#pragma unroll
    for (int nt = 0; nt < 9; ++nt)
#pragma unroll
      for (int r = 0; r < 4; ++r) Oacc[nt][r] *= alv[r];

    // ---- PV: O(16x144) += P(16x32) @ V(32x144); Ps strip wave-local
    {
      f16x8 pa = *(const f16x8*)&Ps[(w * 16 + l16) * 40 + quad * 8];
#pragma unroll
      for (int nt = 0; nt < 9; ++nt) {
        f16x8 vb = *(const f16x8*)&Vs[(quad * 144 + nt * 16 + l16) * 8];
        Oacc[nt] = __builtin_amdgcn_mfma_f32_16x16x32_f16(pa, vb, Oacc[nt], 0, 0, 0);
      }
    }
    __syncthreads();
  }

  // ---- epilogue: write PARTIALS (no normalize, no swizzle)
  const int pid = (b * 4 + hp) * 80 + x;   // slot index == x
  const int hsel = w >> 2;
  _Float16* po = pO + ((size_t)pid * 2 + hsel) * 64 * 144;
#pragma unroll
  for (int nt = 0; nt < 9; ++nt)
#pragma unroll
    for (int r = 0; r < 4; ++r)
      po[(w4 * 16 + quad * 4 + r) * 144 + nt * 16 + l16] = (_Float16)Oacc[nt][r];
  if (l16 == 0) {
    float* pm = pml + ((size_t)pid * 2 + hsel) * 128;
#pragma unroll
    for (int r = 0; r < 4; ++r) {
      pm[(w4 * 16 + quad * 4 + r) * 2 + 0] = mrow[r];
      pm[(w4 * 16 + quad * 4 + r) * 2 + 1] = lrow[r];
    }
  }
}

// ---------------------------------------------------------------- merge partials
// grid (18 d-chunks, 64 row-groups, 8 heads), 128 threads (1/row).
// out = (sum_i e^{m_i-M} O_i) / (sum_i e^{m_i-M} l_i); writes swizzled granule.
__global__ __launch_bounds__(128) void merge_partials(
    const _Float16* __restrict__ pO, const float* __restrict__ pml,
    _Float16* __restrict__ Out) {
  const int j = blockIdx.x, rg = blockIdx.y, h = blockIdx.z;
  const int t = threadIdx.x;
  const int grow = rg * 128 + t;          // global row 0..8191
  const int b = grow >> 11, s = grow & 2047;
  const int qi = s >> 6, r = s & 63;
  const int hp = h >> 1, hs = h & 1;
  int base, nc;
  if (qi < 8)       { base = qi;                nc = 1; }
  else if (qi < 16) { base = 8 + 2 * (qi - 8);  nc = 2; }
  else if (qi < 24) { base = 24 + 3 * (qi - 16); nc = 3; }
  else              { base = 48 + 4 * (qi - 24); nc = 4; }
  const int pb = (b * 4 + hp) * 80 + base;

  float m[4], l[4];
  float M = -3e38f;
  for (int i = 0; i < nc; ++i) {
    const float* p = pml + ((size_t)(pb + i) * 2 + hs) * 128 + r * 2;
    m[i] = p[0];
    l[i] = p[1];
    M = fmaxf(M, m[i]);
  }
  float acc[8] = {};
  float L = 0.f;
  for (int i = 0; i < nc; ++i) {
    const float sc = __expf(m[i] - M);
    L += sc * l[i];
    f16x8 o = *(const f16x8*)(pO + (((size_t)(pb + i) * 2 + hs) * 64 + r) * 144 + j * 8);
#pragma unroll
    for (int e = 0; e < 8; ++e) acc[e] += sc * (float)o[e];
  }
  const float invL = 1.f / L;
  f16x8 out;
#pragma unroll
  for (int e = 0; e < 8; ++e) out[e] = (_Float16)(acc[e] * invL);
  *(f16x8*)(Out + (((size_t)(grow >> 7) * 144 + h * 18 + j) * 128 + (grow & 127)) * 8) = out;
}

// ============================================================================
extern "C" void kernel_launch(void* const* d_in, const int* in_sizes, int n_in,
                              void* d_out, int out_size, void* d_ws, size_t ws_size,
                              hipStream_t stream) {
  const float* x = (const float*)d_in[0];
  const float* wq = (const float*)d_in[1];
  const float* bq = (const float*)d_in[2];
  const float* wkv = (const float*)d_in[3];
  const float* bkv = (const float*)d_in[4];
  const float* wo = (const float*)d_in[5];
  const float* bo = (const float*)d_in[6];
  const float* fc = (const float*)d_in[7];
  const float* fs = (const float*)d_in[8];
  // d_in[9..12] (k_cache, v_cache, mask, start_pos) unused: start_pos=0 prefill.
  float* out = (float*)d_out;
  char* ws = (char*)d_ws;

  _Float16* x_sw = (_Float16*)(ws + 0);
  _Float16* wqkv_sw = (_Float16*)(ws + 18874368);
  _Float16* wo_sw = (_Float16*)(ws + 23003136);
  float* bias_qkv = (float*)(ws + 25657344);
  float* qkv = (float*)(ws + 25664256);
  _Float16* part_O = (_Float16*)(ws + 25664256);   // reuses dead qkv region
  float* part_ml = (float*)(ws + 72850176);        // 25664256 + 47185920
  _Float16* Qh = (_Float16*)(ws + 82287360);
  _Float16* Ksw = (_Float16*)(ws + 101161728);
  _Float16* Vsw = (_Float16*)(ws + 105880320);
  _Float16* attn_sw = (_Float16*)(ws + 110598912);

  // swizzled f16 casts (KC = 1152/8 = 144 granules/row; nG = blocks*144*128)
  cvt_sw<<<4608, THREADS, 0, stream>>>(x, x_sw, 1179648, 144, 8192);
  cvt_sw<<<648, THREADS, 0, stream>>>(wq, wqkv_sw, 165888, 144, 1152);
  cvt_sw<<<360, THREADS, 0, stream>>>(wkv, wqkv_sw + 1327104, 92160, 144, 576);
  cvt_sw<<<648, THREADS, 0, stream>>>(wo, wo_sw, 165888, 144, 1152);
  prep_bias<<<7, THREADS, 0, stream>>>(bq, bkv, bias_qkv);

  gemm_sw<<<dim3(14, 64), THREADS, 0, stream>>>(x_sw, wqkv_sw, bias_qkv, qkv,
                                                8192, 1728, 1152);

  rope_scatter_f16<<<23040, THREADS, 0, stream>>>(qkv, fc, fs, Qh, Ksw);
  v_transpose<<<dim3(16, 2, 4), THREADS, 0, stream>>>(qkv, Vsw);
  // qkv region is now dead -> reused for split-K partials.

  attn_mfma<<<dim3(80, 4, 4), 512, 0, stream>>>(Qh, Ksw, Vsw, part_O, part_ml);
  merge_partials<<<dim3(18, 64, 8), 128, 0, stream>>>(part_O, part_ml, attn_sw);

  gemm_sw<<<dim3(9, 64), THREADS, 0, stream>>>(attn_sw, wo_sw, bo, out, 8192,
                                               1152, 1152);
}

// Round 11
// 420.943 us; speedup vs baseline: 1.0769x; 1.0769x over previous
//
#include <hip/hip_runtime.h>

// ============================================================================
// GQA prefill: B=4, S=2048, DIM=1152, NH=8, KVH=2, HD=144, causal, start_pos=0
//
// R18 = R17 (PASSING; attn 158.6us but merge ~49us made total 453) with the
// merge path overhauled -- same math, fixed addressing:
//  1. pO layout -> [pid][hs][j=18][row=64][8] (d-chunk-major): merge reads
//     fully coalesced (R17's [row][144] gave stride-288B lane reads, ~4x
//     read amplification on 48 MB).
//  2. merge loops static-unrolled over 4 with i<nc guard (R17's runtime-nc
//     loop over float m[4] -> runtime-indexed array -> scratch, rule #20).
//  3. nc==1 blocks (x<8, qi 0..7) write attn_sw DIRECTLY via R10's proven
//     epilogue (block-uniform branch); merge grid covers only s>=512.
//
// R17 (unchanged): split-K attention. Block (x,hp,b), x in [0,80) enumerates
// (qi, chunk c) with chunk=16 k-tiles (nc=ceil(nkt/16)); inner loop R10-
// verbatim over kt in [16c, min(16c+16,nkt)); band=kt>=nkt-2 fires only in
// the last chunk. Partials: pre-normalized O (f16) + m,l (f32) in the dead
// qkv ws region. merge: M=max m_i; out=(sum e^{m_i-M}O_i)/(sum e^{m_i-M}l_i).
// LDS 28672 B; launch_bounds(512,4).
//
// R10 (unchanged): head-pair sharing: waves 0-3 head hp*2, waves 4-7 head
// hp*2+1 (kvh=hp>>1) share one staged K/V tile; per-wave R7-exact TQ=64
// strip (w4=w&3), TK=32, unconditional rescale.
//
// R7 (unchanged): K and Vt pre-swizzled into MFMA-granule order:
//      Ksw granule = (tile*576 + (d>>3)*32 + (s&31)), elem d&7
//      Vsw granule = (tile*576 + ((s&31)>>3)*144 + d), elem s&7
//
// ws layout (bytes):
//   x_sw     :         0 ..  18874368   (8192x1152 f16 swizzled, KC=144)
//   wqkv_sw  :  18874368 ..  23003136   (1792x1152 sw; rows>=1728 pad)
//   wo_sw    :  23003136 ..  25657344
//   bias_qkv :  25657344 ..  25664256
//   qkv f32  :  25664256 ..  82287360   (8192x1728 plain)
//     during attention this region is reused:
//     part_O  :  25664256 ..  72850176   [1280][2][18][64][8] f16
//     part_ml :  72850176 ..  74160896   [1280][2][64][2]  f32
//   Qh       :  82287360 .. 101161728   (4,8,2048,144) f16 plain
//   Ksw      : 101161728 .. 105880320   (4,2) x 64 tiles x 576 granules
//   Vsw      : 105880320 .. 110598912   (4,2) x 64 tiles x 576 granules
//   attn_sw  : 110598912 .. 129473280   (8192x1152 f16 swizzled)
// ============================================================================

#define THREADS 256

typedef _Float16 f16x8 __attribute__((ext_vector_type(8)));
typedef _Float16 f16x4 __attribute__((ext_vector_type(4)));
typedef _Float16 f16x2 __attribute__((ext_vector_type(2)));
typedef float f32x4 __attribute__((ext_vector_type(4)));

// 16B global->LDS DMA: LDS dst = wave-uniform base + lane*16
#define GLDS16(gp, lp)                                                  \
  __builtin_amdgcn_global_load_lds(                                     \
      (const __attribute__((address_space(1))) unsigned int*)(gp),      \
      (__attribute__((address_space(3))) unsigned int*)(lp), 16, 0, 0)

// ---------------------------------------------------------------- cvt -> swizzled
__global__ __launch_bounds__(THREADS) void cvt_sw(const float* __restrict__ in,
                                                  _Float16* __restrict__ out,
                                                  int nG, int KC, int nrows) {
  int i = blockIdx.x * THREADS + threadIdx.x;
  if (i >= nG) return;
  int rr = i & 127;
  int j = i >> 7;
  int kc = j % KC;
  int rb = j / KC;
  int R = rb * 128 + rr;
  if (R >= nrows) R = nrows - 1;
  const float* src = in + (size_t)R * (KC * 8) + kc * 8;
  float4 a = *(const float4*)src;
  float4 c = *(const float4*)(src + 4);
  f16x8 o;
  o[0] = (_Float16)a.x; o[1] = (_Float16)a.y;
  o[2] = (_Float16)a.z; o[3] = (_Float16)a.w;
  o[4] = (_Float16)c.x; o[5] = (_Float16)c.y;
  o[6] = (_Float16)c.z; o[7] = (_Float16)c.w;
  *(f16x8*)(out + (size_t)i * 8) = o;
}

// ---------------------------------------------------------------- bias concat
__global__ __launch_bounds__(THREADS) void prep_bias(const float* __restrict__ bq,
                                                     const float* __restrict__ bkv,
                                                     float* __restrict__ bias) {
  int i = blockIdx.x * THREADS + threadIdx.x;
  if (i < 1152) bias[i] = bq[i];
  else if (i < 1728) bias[i] = bkv[i - 1152];
}

// ---------------------------------------------------------------- GEMM (swizzled)
__global__ __launch_bounds__(THREADS) void gemm_sw(
    const _Float16* __restrict__ A, const _Float16* __restrict__ B,
    const float* __restrict__ bias, float* __restrict__ C, int M, int N, int K) {
  __shared__ __align__(16) _Float16 As[1024 * 8];
  __shared__ __align__(16) _Float16 Bs[1024 * 8];
  const int t = threadIdx.x;
  const int w = t >> 6, lane = t & 63;
  const int quad = lane >> 4, l16 = lane & 15;
  const int wm = (w & 1) << 6, wn = (w >> 1) << 6;
  const int KC = K >> 3;
  const int mb = blockIdx.y, nb = blockIdx.x;
  const int m0 = mb << 7, n0 = nb << 7;

  f32x4 acc[4][4] = {};

  for (int kcb = 0; kcb < KC; kcb += 8) {
    const size_t Ab = ((size_t)mb * KC + kcb) << 7;
    const size_t Bb = ((size_t)nb * KC + kcb) << 7;
#pragma unroll
    for (int j = 0; j < 4; ++j) {
      const int ii = (w << 2) + j;
      GLDS16(A + ((Ab + (ii << 6) + lane) << 3), &As[(ii << 6) * 8]);
      GLDS16(B + ((Bb + (ii << 6) + lane) << 3), &Bs[(ii << 6) * 8]);
    }
    __syncthreads();
#pragma unroll
    for (int ks = 0; ks < 2; ++ks) {
      f16x8 af[4], bf[4];
#pragma unroll
      for (int mi = 0; mi < 4; ++mi)
        af[mi] = *(const f16x8*)&As[((((ks << 2) + quad) << 7) + wm + (mi << 4) + l16) * 8];
#pragma unroll
      for (int ni = 0; ni < 4; ++ni)
        bf[ni] = *(const f16x8*)&Bs[((((ks << 2) + quad) << 7) + wn + (ni << 4) + l16) * 8];
#pragma unroll
      for (int mi = 0; mi < 4; ++mi)
#pragma unroll
        for (int ni = 0; ni < 4; ++ni)
          acc[mi][ni] =
              __builtin_amdgcn_mfma_f32_16x16x32_f16(af[mi], bf[ni], acc[mi][ni], 0, 0, 0);
    }
    __syncthreads();
  }

#pragma unroll
  for (int mi = 0; mi < 4; ++mi) {
    const int row = m0 + wm + (mi << 4) + (quad << 2);
#pragma unroll
    for (int ni = 0; ni < 4; ++ni) {
      const int col = n0 + wn + (ni << 4) + l16;
      if (col < N) {
        const float bv = bias[col];
#pragma unroll
        for (int r = 0; r < 4; ++r)
          C[(size_t)(row + r) * N + col] = acc[mi][ni][r] + bv;
      }
    }
  }
}

// ---------------------------------------------------------------- RoPE
__global__ __launch_bounds__(THREADS) void rope_scatter_f16(
    const float* __restrict__ qkv, const float* __restrict__ fc,
    const float* __restrict__ fs, _Float16* __restrict__ Qh,
    _Float16* __restrict__ Ksw) {
  int idx = blockIdx.x * THREADS + threadIdx.x;
  int m = idx / 720;
  int c = idx - m * 720;
  int s = m & 2047, b = m >> 11;
  const float* row = qkv + (size_t)m * 1728;
  int h, d2;
  const float* src;
  _Float16* dst;
  if (c < 576) {
    h = c / 72;
    d2 = c - h * 72;
    src = row + h * 144 + 2 * d2;
    dst = Qh + ((size_t)(b * 8 + h) * 2048 + s) * 144 + 2 * d2;
  } else {
    int cc = c - 576;
    h = cc / 72;  // kvh
    d2 = cc - h * 72;
    src = row + 1152 + h * 144 + 2 * d2;
    size_t g = ((size_t)(b * 2 + h) * 64 + (s >> 5)) * 576 + (d2 >> 2) * 32 + (s & 31);
    dst = Ksw + g * 8 + (d2 & 3) * 2;
  }
  float2 v = *(const float2*)src;
  float cth = fc[s * 72 + d2], sth = fs[s * 72 + d2];
  f16x2 o;
  o.x = (_Float16)(v.x * cth - v.y * sth);
  o.y = (_Float16)(v.x * sth + v.y * cth);
  *(f16x2*)dst = o;
}

// ---------------------------------------------------------------- V -> swizzled
__global__ __launch_bounds__(THREADS) void v_transpose(const float* __restrict__ qkv,
                                                       _Float16* __restrict__ Vsw) {
  __shared__ _Float16 tile[128 * 145];
  const int t = threadIdx.x;
  const int s0 = blockIdx.x * 128;
  const int kvh = blockIdx.y, b = blockIdx.z;
  const float* src = qkv + ((size_t)(b * 2048 + s0)) * 1728 + 1440 + kvh * 144;
#pragma unroll
  for (int i = 0; i < 18; ++i) {
    int c = t + i * 256;
    int r = c / 36, cc = c - r * 36;
    float4 v = *(const float4*)(src + (size_t)r * 1728 + cc * 4);
    int base = r * 145 + cc * 4;
    tile[base + 0] = (_Float16)v.x;
    tile[base + 1] = (_Float16)v.y;
    tile[base + 2] = (_Float16)v.z;
    tile[base + 3] = (_Float16)v.w;
  }
  __syncthreads();
  const size_t tb = ((size_t)(b * 2 + kvh) * 64 + (s0 >> 5)) * 576;
#pragma unroll
  for (int i = 0; i < 9; ++i) {
    int c = t + i * 256;
    int sc = c / 144, d = c - sc * 144;
    f16x8 o;
#pragma unroll
    for (int j = 0; j < 8; ++j) o[j] = tile[(sc * 8 + j) * 145 + d];
    size_t g = tb + (size_t)(sc >> 2) * 576 + (sc & 3) * 144 + d;
    *(f16x8*)(Vsw + g * 8) = o;
  }
}

// ---------------------------------------------------------------- MFMA flash attention (split-K chunk)
#define STAGE_TILE(kt)                                                     \
  do {                                                                     \
    const _Float16* Kt_ = Ksw + (tbase + (size_t)(kt)) * 4608;             \
    const _Float16* Vt_ = Vsw + (tbase + (size_t)(kt)) * 4608;             \
    for (int cc_ = w; cc_ < 18; cc_ += 8) {                                \
      if (cc_ < 9)                                                         \
        GLDS16(Kt_ + ((cc_ << 6) + lane) * 8, &Ks[(cc_ << 6) * 8]);        \
      else                                                                 \
        GLDS16(Vt_ + (((cc_ - 9) << 6) + lane) * 8,                        \
               &Vs[((cc_ - 9) << 6) * 8]);                                 \
    }                                                                      \
  } while (0)

__global__ __launch_bounds__(512, 4) void attn_mfma(
    const _Float16* __restrict__ Qh, const _Float16* __restrict__ Ksw,
    const _Float16* __restrict__ Vsw, _Float16* __restrict__ pO,
    float* __restrict__ pml, _Float16* __restrict__ Out) {
  __shared__ __align__(16) _Float16 Ks[576 * 8];
  __shared__ __align__(16) _Float16 Vs[576 * 8];
  __shared__ __align__(16) _Float16 Ps[128 * 40];
  const int t = threadIdx.x;
  const int w = t >> 6, lane = t & 63;
  const int w4 = w & 3;
  const int quad = lane >> 4, l16 = lane & 15;
  const int x = blockIdx.x, hp = blockIdx.y, b = blockIdx.z;
  const int h = hp * 2 + (w >> 2);
  const int kvh = hp >> 1;

  // slot x -> (qi, c)
  int qi, c;
  if (x < 8)       { qi = x;                 c = 0; }
  else if (x < 24) { qi = 8 + ((x - 8) >> 1);  c = (x - 8) & 1; }
  else if (x < 48) { qi = 16 + (x - 24) / 3;   c = (x - 24) % 3; }
  else             { qi = 24 + ((x - 48) >> 2); c = (x - 48) & 3; }

  const int q0 = qi * 64;
  const int nkt = 2 * qi + 2;
  const int k0 = c * 16;
  const int kend = (k0 + 16 < nkt) ? k0 + 16 : nkt;
  const _Float16* Qg = Qh + ((size_t)(b * 8 + h) * 2048 + q0) * 144;
  const size_t tbase = (size_t)(b * 2 + kvh) * 64;

  // Q fragments: rows w4*16 + l16
  f16x8 qf[4];
  f16x4 qt4;
  {
    const _Float16* qp = Qg + (size_t)(w4 * 16 + l16) * 144;
#pragma unroll
    for (int ks = 0; ks < 4; ++ks) qf[ks] = *(const f16x8*)(qp + ks * 32 + quad * 8);
    qt4 = *(const f16x4*)(qp + 128 + quad * 4);
  }

  f32x4 Oacc[9] = {};
  float mrow[4] = {-3e38f, -3e38f, -3e38f, -3e38f};
  float lrow[4] = {0.f, 0.f, 0.f, 0.f};
  const float scale = 0.08333333333333333f;  // 1/sqrt(144)
  const int colb = (l16 & ~1);
  const int rsel = (lane & 1) << 1;

  for (int kt = k0; kt < kend; ++kt) {
    STAGE_TILE(kt);
    __syncthreads();

    // ---- QK^T: 16 rows x 32 keys
    f32x4 sc[2] = {};
#pragma unroll
    for (int ks = 0; ks < 4; ++ks) {
#pragma unroll
      for (int ct = 0; ct < 2; ++ct) {
        f16x8 bfr = *(const f16x8*)&Ks[(((ks * 4 + quad) << 5) + ct * 16 + l16) * 8];
        sc[ct] = __builtin_amdgcn_mfma_f32_16x16x32_f16(qf[ks], bfr, sc[ct], 0, 0, 0);
      }
    }
#pragma unroll
    for (int ct = 0; ct < 2; ++ct) {  // k=128..143 tail (legacy 16x16x16)
      f16x4 bt = *(const f16x4*)&Ks[(((16 + (quad >> 1)) << 5) + ct * 16 + l16) * 8 +
                                    (quad & 1) * 4];
      sc[ct] = __builtin_amdgcn_mfma_f32_16x16x16f16(qt4, bt, sc[ct], 0, 0, 0);
    }

    // ---- online softmax (rows q0+w4*16+quad*4+r, cols kt*32+ct*16+l16)
    const bool band = (kt >= nkt - 2);   // fires only in the last chunk
    const int rowb = q0 + w4 * 16 + quad * 4;
    float vv[2][4];
    float mx[4] = {-3e38f, -3e38f, -3e38f, -3e38f};
#pragma unroll
    for (int ct = 0; ct < 2; ++ct) {
      const int cb = kt * 32 + ct * 16 + l16;
#pragma unroll
      for (int r = 0; r < 4; ++r) {
        float v = sc[ct][r] * scale;
        if (band && cb > rowb + r) v -= 1e9f;
        vv[ct][r] = v;
        mx[r] = fmaxf(mx[r], v);
      }
    }
    float alv[4];
#pragma unroll
    for (int r = 0; r < 4; ++r) {
      float m = mx[r];
      m = fmaxf(m, __shfl_xor(m, 1));
      m = fmaxf(m, __shfl_xor(m, 2));
      m = fmaxf(m, __shfl_xor(m, 4));
      m = fmaxf(m, __shfl_xor(m, 8));
      float mn = fmaxf(mrow[r], m);
      alv[r] = __expf(mrow[r] - mn);
      mrow[r] = mn;
    }
    float rs[4] = {0.f, 0.f, 0.f, 0.f};
#pragma unroll
    for (int ct = 0; ct < 2; ++ct) {
      float p[4], q[4];
#pragma unroll
      for (int r = 0; r < 4; ++r) {
        p[r] = __expf(vv[ct][r] - mrow[r]);
        rs[r] += p[r];
      }
#pragma unroll
      for (int r = 0; r < 4; ++r) q[r] = __shfl_xor(p[r], 1);
#pragma unroll
      for (int k = 0; k < 2; ++k) {
        const int r = rsel + k;
        f16x2 pv;
        if (lane & 1) {
          pv.x = (_Float16)q[r];
          pv.y = (_Float16)p[r];
        } else {
          pv.x = (_Float16)p[r];
          pv.y = (_Float16)q[r];
        }
        *(f16x2*)&Ps[(w * 16 + quad * 4 + r) * 40 + ct * 16 + colb] = pv;
      }
    }
#pragma unroll
    for (int r = 0; r < 4; ++r) {
      float v = rs[r];
      v += __shfl_xor(v, 1);
      v += __shfl_xor(v, 2);
      v += __shfl_xor(v, 4);
      v += __shfl_xor(v, 8);
      lrow[r] = lrow[r] * alv[r] + v;
    }
#pragma unroll
    for (int nt = 0; nt < 9; ++nt)
#pragma unroll
      for (int r = 0; r < 4; ++r) Oacc[nt][r] *= alv[r];

    // ---- PV: O(16x144) += P(16x32) @ V(32x144); Ps strip wave-local
    {
      f16x8 pa = *(const f16x8*)&Ps[(w * 16 + l16) * 40 + quad * 8];
#pragma unroll
      for (int nt = 0; nt < 9; ++nt) {
        f16x8 vb = *(const f16x8*)&Vs[(quad * 144 + nt * 16 + l16) * 8];
        Oacc[nt] = __builtin_amdgcn_mfma_f32_16x16x32_f16(pa, vb, Oacc[nt], 0, 0, 0);
      }
    }
    __syncthreads();
  }

  if (x < 8) {
    // ---- nc==1: normalize + swizzled attn_sw write (R10 epilogue verbatim)
    float inv[4];
#pragma unroll
    for (int r = 0; r < 4; ++r) inv[r] = 1.f / lrow[r];
#pragma unroll
    for (int nt = 0; nt < 9; ++nt) {
      float o[4], qn[4];
#pragma unroll
      for (int r = 0; r < 4; ++r) o[r] = Oacc[nt][r] * inv[r];
#pragma unroll
      for (int r = 0; r < 4; ++r) qn[r] = __shfl_xor(o[r], 1);
#pragma unroll
      for (int k = 0; k < 2; ++k) {
        const int r = rsel + k;
        f16x2 pv;
        if (lane & 1) {
          pv.x = (_Float16)qn[r];
          pv.y = (_Float16)o[r];
        } else {
          pv.x = (_Float16)o[r];
          pv.y = (_Float16)qn[r];
        }
        const size_t grow = (size_t)b * 2048 + q0 + w4 * 16 + quad * 4 + r;
        const size_t g = ((grow >> 7) * 144 + h * 18 + nt * 2 + (colb >> 3)) * 128 +
                         (grow & 127);
        *(f16x2*)(Out + g * 8 + (colb & 7)) = pv;
      }
    }
  } else {
    // ---- partials: pO[pid][hs][j=18][row=64][8] (d-chunk-major, coalesced merge)
    const int pid = (b * 4 + hp) * 80 + x;
    const int hsel = w >> 2;
    _Float16* po = pO + ((size_t)pid * 2 + hsel) * 9216;
    const int row = w4 * 16 + quad * 4;
#pragma unroll
    for (int nt = 0; nt < 9; ++nt)
#pragma unroll
      for (int r = 0; r < 4; ++r)
        po[(((nt << 1) + (l16 >> 3)) * 64 + row + r) * 8 + (l16 & 7)] =
            (_Float16)Oacc[nt][r];
    if (l16 == 0) {
      float* pm = pml + ((size_t)pid * 2 + hsel) * 128;
#pragma unroll
      for (int r = 0; r < 4; ++r) {
        pm[(row + r) * 2 + 0] = mrow[r];
        pm[(row + r) * 2 + 1] = lrow[r];
      }
    }
  }
}

// ---------------------------------------------------------------- merge partials
// Only rows s >= 512 (qi >= 8). grid (18 d-chunks, 48 row-groups, 8 heads),
// 128 threads. Coalesced pO reads (d-chunk-major layout); static-unrolled
// nc loop (no scratch). out = (sum e^{m_i-M} O_i) / (sum e^{m_i-M} l_i).
__global__ __launch_bounds__(128) void merge_partials(
    const _Float16* __restrict__ pO, const float* __restrict__ pml,
    _Float16* __restrict__ Out) {
  const int j = blockIdx.x, rg = blockIdx.y, h = blockIdx.z;
  const int t = threadIdx.x;
  const int gidx = rg * 128 + t;          // 0..6143
  const int b = gidx / 1536;
  const int s = 512 + (gidx - b * 1536);  // 512..2047
  const int grow = b * 2048 + s;
  const int qi = s >> 6, r = s & 63;
  const int hp = h >> 1, hs = h & 1;
  int base, nc;
  if (qi < 16)      { base = 8 + 2 * (qi - 8);   nc = 2; }
  else if (qi < 24) { base = 24 + 3 * (qi - 16); nc = 3; }
  else              { base = 48 + 4 * (qi - 24); nc = 4; }
  const int pb = (b * 4 + hp) * 80 + base;

  float mm[4] = {-3e38f, -3e38f, -3e38f, -3e38f};
  float ll[4] = {0.f, 0.f, 0.f, 0.f};
  float M = -3e38f;
#pragma unroll
  for (int i = 0; i < 4; ++i)
    if (i < nc) {
      const float* p = pml + ((size_t)(pb + i) * 2 + hs) * 128 + r * 2;
      mm[i] = p[0];
      ll[i] = p[1];
      M = fmaxf(M, mm[i]);
    }
  float acc[8] = {};
  float L = 0.f;
#pragma unroll
  for (int i = 0; i < 4; ++i)
    if (i < nc) {
      const float sc = __expf(mm[i] - M);
      L += sc * ll[i];
      f16x8 o = *(const f16x8*)(pO + (((size_t)(pb + i) * 2 + hs) * 1152 +
                                      (size_t)(j * 64 + r)) * 8);
#pragma unroll
      for (int e = 0; e < 8; ++e) acc[e] += sc * (float)o[e];
    }
  const float invL = 1.f / L;
  f16x8 out;
#pragma unroll
  for (int e = 0; e < 8; ++e) out[e] = (_Float16)(acc[e] * invL);
  *(f16x8*)(Out + (((size_t)(grow >> 7) * 144 + h * 18 + j) * 128 + (grow & 127)) * 8) = out;
}

// ============================================================================
extern "C" void kernel_launch(void* const* d_in, const int* in_sizes, int n_in,
                              void* d_out, int out_size, void* d_ws, size_t ws_size,
                              hipStream_t stream) {
  const float* x = (const float*)d_in[0];
  const float* wq = (const float*)d_in[1];
  const float* bq = (const float*)d_in[2];
  const float* wkv = (const float*)d_in[3];
  const float* bkv = (const float*)d_in[4];
  const float* wo = (const float*)d_in[5];
  const float* bo = (const float*)d_in[6];
  const float* fc = (const float*)d_in[7];
  const float* fs = (const float*)d_in[8];
  // d_in[9..12] (k_cache, v_cache, mask, start_pos) unused: start_pos=0 prefill.
  float* out = (float*)d_out;
  char* ws = (char*)d_ws;

  _Float16* x_sw = (_Float16*)(ws + 0);
  _Float16* wqkv_sw = (_Float16*)(ws + 18874368);
  _Float16* wo_sw = (_Float16*)(ws + 23003136);
  float* bias_qkv = (float*)(ws + 25657344);
  float* qkv = (float*)(ws + 25664256);
  _Float16* part_O = (_Float16*)(ws + 25664256);   // reuses dead qkv region
  float* part_ml = (float*)(ws + 72850176);
  _Float16* Qh = (_Float16*)(ws + 82287360);
  _Float16* Ksw = (_Float16*)(ws + 101161728);
  _Float16* Vsw = (_Float16*)(ws + 105880320);
  _Float16* attn_sw = (_Float16*)(ws + 110598912);

  // swizzled f16 casts (KC = 1152/8 = 144 granules/row; nG = blocks*144*128)
  cvt_sw<<<4608, THREADS, 0, stream>>>(x, x_sw, 1179648, 144, 8192);
  cvt_sw<<<648, THREADS, 0, stream>>>(wq, wqkv_sw, 165888, 144, 1152);
  cvt_sw<<<360, THREADS, 0, stream>>>(wkv, wqkv_sw + 1327104, 92160, 144, 576);
  cvt_sw<<<648, THREADS, 0, stream>>>(wo, wo_sw, 165888, 144, 1152);
  prep_bias<<<7, THREADS, 0, stream>>>(bq, bkv, bias_qkv);

  gemm_sw<<<dim3(14, 64), THREADS, 0, stream>>>(x_sw, wqkv_sw, bias_qkv, qkv,
                                                8192, 1728, 1152);

  rope_scatter_f16<<<23040, THREADS, 0, stream>>>(qkv, fc, fs, Qh, Ksw);
  v_transpose<<<dim3(16, 2, 4), THREADS, 0, stream>>>(qkv, Vsw);
  // qkv region is now dead -> reused for split-K partials.

  attn_mfma<<<dim3(80, 4, 4), 512, 0, stream>>>(Qh, Ksw, Vsw, part_O, part_ml,
                                                attn_sw);
  merge_partials<<<dim3(18, 48, 8), 128, 0, stream>>>(part_O, part_ml, attn_sw);

  gemm_sw<<<dim3(9, 64), THREADS, 0, stream>>>(attn_sw, wo_sw, bo, out, 8192,
                                               1152, 1152);
}